// Round 14
// baseline (812.892 us; speedup 1.0000x reference)
//
#include <hip/hip_runtime.h>
#include <hip/hip_fp16.h>

typedef __attribute__((ext_vector_type(8))) short short8;
typedef __attribute__((ext_vector_type(4))) float f32x4;

#define TT 2048
#define DD 512

__device__ __forceinline__ unsigned short f2bf(float f) {
  unsigned int u = __float_as_uint(f);
  u += 0x7FFFu + ((u >> 16) & 1u);
  return (unsigned short)(u >> 16);
}
__device__ __forceinline__ float h2f(unsigned short u) {
  return __half2float(__ushort_as_half(u));
}
__device__ __forceinline__ unsigned int pkrtz(float a, float b) {
  auto r = __builtin_amdgcn_cvt_pkrtz(a, b);   // __fp16 ext_vector_type(2)
  return __builtin_bit_cast(unsigned int, r);
}
__device__ __forceinline__ void gload16(const void* g, void* l) {
  __builtin_amdgcn_global_load_lds((const __attribute__((address_space(1))) void*)g,
                                   (__attribute__((address_space(3))) void*)l, 16, 0, 0);
}

// ---------- prep kernels ----------

__global__ void xconv_kernel(const float* __restrict__ x, unsigned short* __restrict__ xbf) {
  int i = blockIdx.x * 256 + threadIdx.x;
  const float4* p = (const float4*)x + (size_t)i * 2;
  float4 a = p[0], b = p[1];
  short8 o;
  o[0] = f2bf(a.x); o[1] = f2bf(a.y); o[2] = f2bf(a.z); o[3] = f2bf(a.w);
  o[4] = f2bf(b.x); o[5] = f2bf(b.y); o[6] = f2bf(b.z); o[7] = f2bf(b.w);
  *((short8*)xbf + i) = o;
}

// W[512][1536] fp32 -> Wt[dir][n'][512 k] bf16, n' = (h>>6)*192 + gate*64 + (h&63)
__global__ void wtrans_new_kernel(const float* __restrict__ Wf,
                                  const float* __restrict__ Wb,
                                  unsigned short* __restrict__ wt) {
  __shared__ float tile[32][33];
  int bid = blockIdx.x;            // 2 * 16 * 48
  int d   = bid / 768;
  int rem = bid - d * 768;
  int kt = rem & 15;
  int ct = rem >> 4;
  const float* W = d ? Wb : Wf;
  int k0 = kt * 32, c0 = ct * 32;
  int r = threadIdx.x >> 5, c = threadIdx.x & 31;
#pragma unroll
  for (int i = 0; i < 4; i++)
    tile[r + 8*i][c] = W[(size_t)(k0 + r + 8*i) * 1536 + c0 + c];
  __syncthreads();
#pragma unroll
  for (int i = 0; i < 4; i++) {
    int col = c0 + r + 8*i;
    int gate = col >> 9, hh = col & 511;
    int nn = (hh >> 6) * 192 + gate * 64 + (hh & 63);
    wt[((size_t)d * 1536 + nn) * 512 + k0 + c] = f2bf(tile[c][r + 8*i]);
  }
}

// old layout for fallback kernel
__global__ void wtrans_old_kernel(const float* __restrict__ Wf,
                                  const float* __restrict__ Wb,
                                  unsigned short* __restrict__ wt) {
  __shared__ float tile[32][33];
  int bid = blockIdx.x;
  int d   = bid / 768;
  int rem = bid - d * 768;
  int kt = rem & 15;
  int ct = rem >> 4;
  const float* W = d ? Wb : Wf;
  int k0 = kt * 32, c0 = ct * 32;
  int r = threadIdx.x >> 5, c = threadIdx.x & 31;
#pragma unroll
  for (int i = 0; i < 4; i++)
    tile[r + 8*i][c] = W[(size_t)(k0 + r + 8*i) * 1536 + c0 + c];
  __syncthreads();
  unsigned short* outp = wt + ((size_t)d * 1536 + c0) * 512 + k0;
#pragma unroll
  for (int i = 0; i < 4; i++)
    outp[(size_t)(r + 8*i) * 512 + c] = f2bf(tile[c][r + 8*i]);
}

__global__ void cbias_kernel(const float* __restrict__ bf_, const float* __restrict__ bb_,
                             float* __restrict__ cb) {
  int t = blockIdx.x * 256 + threadIdx.x;   // 3072
  int d = t / 1536, cc = t - d * 1536;
  int gate = cc >> 9, hh = cc & 511;
  int nn = (hh >> 6) * 192 + gate * 64 + (hh & 63);
  cb[d * 1536 + nn] = (d ? bb_ : bf_)[cc];
}

// ---------- persistent fused GEMM + activation + full fo-pool scan + direct out ----------
// Round-9 structure with ONE change: B fragments are loaded directly from global
// (wt is 3 MB, L2-resident per XCD) instead of LDS-staged. Only A goes through
// global_load_lds (4 ops behind the barrier drain instead of 10); B loads are
// ordinary per-wave loads the compiler pipelines across barriers with counted vmcnt.
// Epilogue (unchanged, round-9): act -> fp16 gates LDS (releases acc registers early)
// -> 2-level in-LDS scan -> fp32 out direct, coalesced.
__global__ __launch_bounds__(256, 2)
void qrnn_persist_kernel(const unsigned short* __restrict__ xbf,
                         const unsigned short* __restrict__ wtp,
                         const float* __restrict__ cb,
                         float* __restrict__ out) {
  __shared__ __align__(16) char smem[51712];  // staging A 16K @0 (B not staged)
                                              // gates overlay: z@0 f@16384 o@32768 ; abL @49152

  // XCD swizzle: XCD x gets bid2 in [64x,64x+64) -> 4 consecutive b, all (dir,hb)
  int bid = blockIdx.x;                  // grid = 512
  int bid2 = (bid & 7) * 64 + (bid >> 3);
  int b = bid2 >> 4;
  int v = bid2 & 15;
  int dir = v >> 3, hb = v & 7;
  int nbase = dir * 1536 + hb * 192;     // wt row base
  int obase = dir * 512 + hb * 64;       // out channel base

  int tid = threadIdx.x, lane = tid & 63, wv = tid >> 6;
  int l15 = lane & 15, q = lane >> 4;

  // A fragment LDS offsets (ks=0; ks=1 addr = offset ^ 64)
  int aoff[2];
#pragma unroll
  for (int mf = 0; mf < 2; ++mf) {
    int row = wv * 32 + mf * 16 + l15;
    aoff[mf] = row * 128 + ((q * 16) ^ ((row & 7) << 4));
  }

  // B direct-load base: frag(j, kt, ks) at bBase + j*16384 + kt*128 + ks*64
  const char* bBase = (const char*)wtp + (size_t)(nbase + l15) * 1024 + q * 16;

  // bias (persistent)
  float cbv[12];
#pragma unroll
  for (int j = 0; j < 12; ++j)
    cbv[j] = cb[nbase + j * 16 + l15];

  // A staging source row/swizzle (chunk-dependent base added in loop)
  int a_row[4], a_koff[4];
#pragma unroll
  for (int i = 0; i < 4; ++i) {
    int l = tid + 256 * i;
    a_row[i] = l >> 3;
    a_koff[i] = ((l & 7) * 16) ^ ((a_row[i] & 7) << 4);
  }

  int h = tid & 63, sub = tid >> 6;
  const char* zB = smem + h * 256;
  const char* fB = smem + 16384 + h * 256;
  const char* oB = smem + 32768 + h * 256;
  int sx = h << 2;
  float2* abL = (float2*)(smem + 49152);   // [64][5] padded: stride 5

  float c_chunk = 0.f;

  for (int ck = 0; ck < 16; ++ck) {
    size_t m0 = (size_t)b * TT + ck * 128;
    const char* aBase = (const char*)xbf + m0 * 1024;

    f32x4 acc[2][12];
#pragma unroll
    for (int mf = 0; mf < 2; ++mf)
#pragma unroll
      for (int j = 0; j < 12; ++j)
        acc[mf][j] = f32x4{0.f, 0.f, 0.f, 0.f};

    for (int kt = 0; kt < 8; ++kt) {
      __syncthreads();   // kt=0: also protects prev epilogue's LDS reads (WAR)
      int kb = kt * 128;
#pragma unroll
      for (int i = 0; i < 4; ++i)
        gload16(aBase + (size_t)a_row[i] * 1024 + a_koff[i] + kb, smem + tid * 16 + i * 4096);
      __syncthreads();   // A landed for all waves (4 loads behind the drain, not 10)
#pragma unroll
      for (int ks = 0; ks < 2; ++ks) {
        int kx = ks * 64;
        short8 a0 = *(const short8*)(smem + (aoff[0] ^ kx));
        short8 a1 = *(const short8*)(smem + (aoff[1] ^ kx));
#pragma unroll
        for (int g = 0; g < 3; ++g) {
          short8 b0 = *(const short8*)(bBase + (4*g+0) * 16384 + kb + kx);
          short8 b1 = *(const short8*)(bBase + (4*g+1) * 16384 + kb + kx);
          short8 b2 = *(const short8*)(bBase + (4*g+2) * 16384 + kb + kx);
          short8 b3 = *(const short8*)(bBase + (4*g+3) * 16384 + kb + kx);
          acc[0][4*g+0] = __builtin_amdgcn_mfma_f32_16x16x32_bf16(a0, b0, acc[0][4*g+0], 0, 0, 0);
          acc[1][4*g+0] = __builtin_amdgcn_mfma_f32_16x16x32_bf16(a1, b0, acc[1][4*g+0], 0, 0, 0);
          acc[0][4*g+1] = __builtin_amdgcn_mfma_f32_16x16x32_bf16(a0, b1, acc[0][4*g+1], 0, 0, 0);
          acc[1][4*g+1] = __builtin_amdgcn_mfma_f32_16x16x32_bf16(a1, b1, acc[1][4*g+1], 0, 0, 0);
          acc[0][4*g+2] = __builtin_amdgcn_mfma_f32_16x16x32_bf16(a0, b2, acc[0][4*g+2], 0, 0, 0);
          acc[1][4*g+2] = __builtin_amdgcn_mfma_f32_16x16x32_bf16(a1, b2, acc[1][4*g+2], 0, 0, 0);
          acc[0][4*g+3] = __builtin_amdgcn_mfma_f32_16x16x32_bf16(a0, b3, acc[0][4*g+3], 0, 0, 0);
          acc[1][4*g+3] = __builtin_amdgcn_mfma_f32_16x16x32_bf16(a1, b3, acc[1][4*g+3], 0, 0, 0);
        }
      }
    }

    __builtin_amdgcn_s_barrier();   // all waves' kt=7 ds_reads consumed; overlay gates

    // gates -> LDS fp16 [gate][h=64 rows of 256B][t-pair u32], byte = (2*t) ^ (h<<2)
    // (releases the 96 acc registers before the scan -> no spills)
#pragma unroll
    for (int mf = 0; mf < 2; ++mf) {
      int base_t = wv * 32 + mf * 16 + (lane >> 4) * 4;
#pragma unroll
      for (int j = 0; j < 12; ++j) {
        int g = j >> 2;
        int hsub = (j & 3) * 16 + l15;
        float vv[4], a[4];
#pragma unroll
        for (int r = 0; r < 4; ++r) vv[r] = acc[mf][j][r] + cbv[j];
        if (g == 0) {
#pragma unroll
          for (int r = 0; r < 4; ++r) {
            float e = __expf(2.f * vv[r]);
            a[r] = 1.f - 2.f * __builtin_amdgcn_rcpf(e + 1.f);
          }
        } else {
#pragma unroll
          for (int r = 0; r < 4; ++r)
            a[r] = __builtin_amdgcn_rcpf(1.f + __expf(-vv[r]));
        }
        char* gp = smem + g * 16384 + hsub * 256;
        int sw = hsub << 2;
        *(unsigned int*)(gp + ((2 * base_t) ^ sw))     = pkrtz(a[0], a[1]);
        *(unsigned int*)(gp + ((2 * base_t + 4) ^ sw)) = pkrtz(a[2], a[3]);
      }
    }

    __syncthreads();

    // pass 1: thread (h, sub) reduces its 32-t segment to (A,B); caches gate words
    unsigned int zw[16], fw[16];
    float A = 1.f, Bv = 0.f;
#pragma unroll
    for (int i = 0; i < 16; ++i) {
      int byo = (sub * 64 + 4 * i) ^ sx;
      zw[i] = *(const unsigned int*)(zB + byo);
      fw[i] = *(const unsigned int*)(fB + byo);
      float z0 = h2f((unsigned short)zw[i]), z1 = h2f((unsigned short)(zw[i] >> 16));
      float f0 = h2f((unsigned short)fw[i]), f1 = h2f((unsigned short)(fw[i] >> 16));
      Bv = f0 * Bv + (1.f - f0) * z0;
      Bv = f1 * Bv + (1.f - f1) * z1;
      A *= f0 * f1;
    }
    abL[h * 5 + sub] = float2{A, Bv};

    __syncthreads();

    // compose: segment-start c for this sub, and chunk-exit c (identical in all 4 subs)
    float cs = c_chunk, cn = c_chunk;
#pragma unroll
    for (int s = 0; s < 4; ++s) {
      float2 ab = abL[h * 5 + s];
      if (s == sub) cs = cn;
      cn = ab.x * cn + ab.y;
    }
    c_chunk = cn;

    // pass 2: rescan from cs (gate words cached in regs; only o read from LDS), write out
    float c = cs;
    float* op = out + (m0 + sub * 32) * 1024 + obase + h;
#pragma unroll
    for (int i = 0; i < 16; ++i) {
      int byo = (sub * 64 + 4 * i) ^ sx;
      unsigned int oo = *(const unsigned int*)(oB + byo);
      float z0 = h2f((unsigned short)zw[i]), z1 = h2f((unsigned short)(zw[i] >> 16));
      float f0 = h2f((unsigned short)fw[i]), f1 = h2f((unsigned short)(fw[i] >> 16));
      float o0 = h2f((unsigned short)oo), o1 = h2f((unsigned short)(oo >> 16));
      c = f0 * c + (1.f - f0) * z0;
      op[0] = o0 * c;
      c = f1 * c + (1.f - f1) * z1;
      op[1024] = o1 * c;
      op += 2048;
    }
  }
}

// ---------- round-1 fused fallback (tiny-ws path; old W layout) ----------
#define NB 192
#define BT 64
__global__ __launch_bounds__(256, 2)
void qrnn_kernel(const float* __restrict__ x,
                 const float* __restrict__ bf_, const float* __restrict__ bb_,
                 const unsigned short* __restrict__ wt,
                 float* __restrict__ out) {
  __shared__ __align__(16) unsigned short sA[64 * 64];
  __shared__ float sG[64 * 193];
  __shared__ float sBias[NB];
  const int tid  = threadIdx.x;
  const int lane = tid & 63;
  const int wv   = tid >> 6;
  int p = blockIdx.x;
  int xcd = p & 7, slot = p >> 3;
  int b   = xcd * 4 + (slot >> 4);
  int v   = slot & 15;
  int dir = v >> 3, ht = v & 7;
  int h0  = ht * 64;
  if (tid < NB) {
    const float* bsrc = dir ? bb_ : bf_;
    sBias[tid] = bsrc[((tid >> 6) << 9) + h0 + (tid & 63)];
  }
  const float* xb = x + (size_t)b * TT * DD;
  const unsigned short* wtd = wt + (size_t)dir * 1536 * 512;
  size_t brow[3];
#pragma unroll
  for (int j = 0; j < 3; j++) {
    int n = 48 * wv + 16 * j + (lane & 15);
    brow[j] = (size_t)(((n >> 6) << 9) + h0 + (n & 63)) * 512 + 8 * (lane >> 4);
  }
  int a_off[2][4];
#pragma unroll
  for (int kk = 0; kk < 2; kk++)
#pragma unroll
    for (int m = 0; m < 4; m++) {
      int row = 16 * m + (lane & 15);
      a_off[kk][m] = row * 128 + ((64 * kk + 16 * (lane >> 4)) ^ ((row & 7) << 4));
    }
  int s_trow[4], s_kq[4], s_woff[4];
#pragma unroll
  for (int i = 0; i < 4; i++) {
    int q = tid + 256 * i;
    s_trow[i] = q >> 4;
    s_kq[i]   = q & 15;
    s_woff[i] = s_trow[i] * 128 + ((8 * s_kq[i]) ^ ((s_trow[i] & 7) << 4));
  }
  float c = 0.f;
  f32x4 acc[4][3];
  for (int t0 = 0; t0 < TT; t0 += BT) {
#pragma unroll
    for (int m = 0; m < 4; m++)
#pragma unroll
      for (int j = 0; j < 3; j++)
        acc[m][j] = f32x4{0.f, 0.f, 0.f, 0.f};
    float4 vv[4];
#pragma unroll
    for (int i = 0; i < 4; i++)
      vv[i] = *(const float4*)(xb + (size_t)(t0 + s_trow[i]) * DD + 4 * s_kq[i]);
#pragma unroll
    for (int ks = 0; ks < 8; ks++) {
      __syncthreads();
#pragma unroll
      for (int i = 0; i < 4; i++) {
        ushort4 u;
        u.x = f2bf(vv[i].x); u.y = f2bf(vv[i].y);
        u.z = f2bf(vv[i].z); u.w = f2bf(vv[i].w);
        *(ushort4*)((char*)sA + s_woff[i]) = u;
      }
      if (ks < 7) {
        int k0n = (ks + 1) * 64;
#pragma unroll
        for (int i = 0; i < 4; i++)
          vv[i] = *(const float4*)(xb + (size_t)(t0 + s_trow[i]) * DD + k0n + 4 * s_kq[i]);
      }
      __syncthreads();
      const char* sAb = (const char*)sA;
      int k0 = ks * 64;
#pragma unroll
      for (int kk = 0; kk < 2; kk++) {
        short8 bfr[3];
#pragma unroll
        for (int j = 0; j < 3; j++)
          bfr[j] = *(const short8*)(wtd + brow[j] + k0 + 32 * kk);
#pragma unroll
        for (int m = 0; m < 4; m++) {
          short8 afr = *(const short8*)(sAb + a_off[kk][m]);
#pragma unroll
          for (int j = 0; j < 3; j++)
            acc[m][j] = __builtin_amdgcn_mfma_f32_16x16x32_bf16(afr, bfr[j], acc[m][j], 0, 0, 0);
        }
      }
    }
#pragma unroll
    for (int m = 0; m < 4; m++)
#pragma unroll
      for (int j = 0; j < 3; j++) {
        int col   = 48 * wv + 16 * j + (lane & 15);
        int rbase = 16 * m + 4 * (lane >> 4);
#pragma unroll
        for (int r = 0; r < 4; r++)
          sG[(rbase + r) * 193 + col] = acc[m][j][r];
      }
    __syncthreads();
    for (int idx = tid; idx < 64 * NB; idx += 256) {
      int t = idx / NB;
      int n = idx - t * NB;
      float g = sG[t * 193 + n] + sBias[n];
      float res;
      if (n < 64) { float e = __expf(2.f * g); res = 1.f - 2.f / (e + 1.f); }
      else        { res = 1.f / (1.f + __expf(-g)); }
      sG[t * 193 + n] = res;
    }
    __syncthreads();
    if (tid < 64) {
      float* og = out + ((size_t)(b * TT + t0)) * 1024 + (dir << 9) + h0 + tid;
      float cc = c;
#pragma unroll 8
      for (int t = 0; t < BT; t++) {
        float z = sG[t * 193 + tid];
        float f = sG[t * 193 + 64 + tid];
        float o = sG[t * 193 + 128 + tid];
        cc = z + f * (cc - z);
        og[(size_t)t << 10] = o * cc;
      }
      c = cc;
    }
  }
}

extern "C" void kernel_launch(void* const* d_in, const int* in_sizes, int n_in,
                              void* d_out, int out_size, void* d_ws, size_t ws_size,
                              hipStream_t stream) {
  const float* x   = (const float*)d_in[0];
  const float* W_f = (const float*)d_in[1];
  const float* b_f = (const float*)d_in[2];
  const float* W_b = (const float*)d_in[3];
  const float* b_b = (const float*)d_in[4];
  float* out = (float*)d_out;

  char* ws = (char*)d_ws;
  const size_t OFF_WT  = 0;                    // 3 MiB
  const size_t OFF_CB  = 3145728;              // 12 KiB
  const size_t OFF_XBF = 3158016;              // 64 MiB
  const size_t NEED    = OFF_XBF + 67108864ull; // ~70.3 MB

  unsigned short* wt  = (unsigned short*)(ws + OFF_WT);
  float* cbias        = (float*)(ws + OFF_CB);
  unsigned short* xbf = (unsigned short*)(ws + OFF_XBF);

  if (ws_size >= NEED) {
    xconv_kernel<<<16384, 256, 0, stream>>>(x, xbf);
    wtrans_new_kernel<<<1536, 256, 0, stream>>>(W_f, W_b, wt);
    cbias_kernel<<<12, 256, 0, stream>>>(b_f, b_b, cbias);
    qrnn_persist_kernel<<<512, 256, 0, stream>>>(xbf, wt, cbias, out);
  } else {
    wtrans_old_kernel<<<1536, 256, 0, stream>>>(W_f, W_b, wt);
    qrnn_kernel<<<512, 256, 0, stream>>>(x, b_f, b_b, wt, out);
  }
}

// Round 15
// 306.006 us; speedup vs baseline: 2.6565x; 2.6565x over previous
//
#include <hip/hip_runtime.h>
#include <hip/hip_fp16.h>

typedef __attribute__((ext_vector_type(8))) short short8;
typedef __attribute__((ext_vector_type(4))) float f32x4;

#define TT 2048
#define DD 512

__device__ __forceinline__ unsigned short f2bf(float f) {
  unsigned int u = __float_as_uint(f);
  u += 0x7FFFu + ((u >> 16) & 1u);
  return (unsigned short)(u >> 16);
}
__device__ __forceinline__ float h2f(unsigned short u) {
  return __half2float(__ushort_as_half(u));
}
__device__ __forceinline__ unsigned int pkrtz(float a, float b) {
  auto r = __builtin_amdgcn_cvt_pkrtz(a, b);   // __fp16 ext_vector_type(2)
  return __builtin_bit_cast(unsigned int, r);
}
__device__ __forceinline__ void gload16(const void* g, void* l) {
  __builtin_amdgcn_global_load_lds((const __attribute__((address_space(1))) void*)g,
                                   (__attribute__((address_space(3))) void*)l, 16, 0, 0);
}

// ---------- prep kernels ----------

__global__ void xconv_kernel(const float* __restrict__ x, unsigned short* __restrict__ xbf) {
  int i = blockIdx.x * 256 + threadIdx.x;
  const float4* p = (const float4*)x + (size_t)i * 2;
  float4 a = p[0], b = p[1];
  short8 o;
  o[0] = f2bf(a.x); o[1] = f2bf(a.y); o[2] = f2bf(a.z); o[3] = f2bf(a.w);
  o[4] = f2bf(b.x); o[5] = f2bf(b.y); o[6] = f2bf(b.z); o[7] = f2bf(b.w);
  *((short8*)xbf + i) = o;
}

// W[512][1536] fp32 -> Wt[dir][n'][512 k] bf16, n' = (h>>6)*192 + gate*64 + (h&63)
__global__ void wtrans_new_kernel(const float* __restrict__ Wf,
                                  const float* __restrict__ Wb,
                                  unsigned short* __restrict__ wt) {
  __shared__ float tile[32][33];
  int bid = blockIdx.x;            // 2 * 16 * 48
  int d   = bid / 768;
  int rem = bid - d * 768;
  int kt = rem & 15;
  int ct = rem >> 4;
  const float* W = d ? Wb : Wf;
  int k0 = kt * 32, c0 = ct * 32;
  int r = threadIdx.x >> 5, c = threadIdx.x & 31;
#pragma unroll
  for (int i = 0; i < 4; i++)
    tile[r + 8*i][c] = W[(size_t)(k0 + r + 8*i) * 1536 + c0 + c];
  __syncthreads();
#pragma unroll
  for (int i = 0; i < 4; i++) {
    int col = c0 + r + 8*i;
    int gate = col >> 9, hh = col & 511;
    int nn = (hh >> 6) * 192 + gate * 64 + (hh & 63);
    wt[((size_t)d * 1536 + nn) * 512 + k0 + c] = f2bf(tile[c][r + 8*i]);
  }
}

// old layout for fallback kernel
__global__ void wtrans_old_kernel(const float* __restrict__ Wf,
                                  const float* __restrict__ Wb,
                                  unsigned short* __restrict__ wt) {
  __shared__ float tile[32][33];
  int bid = blockIdx.x;
  int d   = bid / 768;
  int rem = bid - d * 768;
  int kt = rem & 15;
  int ct = rem >> 4;
  const float* W = d ? Wb : Wf;
  int k0 = kt * 32, c0 = ct * 32;
  int r = threadIdx.x >> 5, c = threadIdx.x & 31;
#pragma unroll
  for (int i = 0; i < 4; i++)
    tile[r + 8*i][c] = W[(size_t)(k0 + r + 8*i) * 1536 + c0 + c];
  __syncthreads();
  unsigned short* outp = wt + ((size_t)d * 1536 + c0) * 512 + k0;
#pragma unroll
  for (int i = 0; i < 4; i++)
    outp[(size_t)(r + 8*i) * 512 + c] = f2bf(tile[c][r + 8*i]);
}

__global__ void cbias_kernel(const float* __restrict__ bf_, const float* __restrict__ bb_,
                             float* __restrict__ cb) {
  int t = blockIdx.x * 256 + threadIdx.x;   // 3072
  int d = t / 1536, cc = t - d * 1536;
  int gate = cc >> 9, hh = cc & 511;
  int nn = (hh >> 6) * 192 + gate * 64 + (hh & 63);
  cb[d * 1536 + nn] = (d ? bb_ : bf_)[cc];
}

// ---------- persistent fused GEMM + activation + full fo-pool scan + direct out ----------
// Block = (b, dir, 64-h band). Loops 16 chunks of 128 t, carrying c in registers.
// Per chunk: round-5 GEMM core (128t x 192n, BK=64, gload16, (row&7)<<4 swizzle,
// 2 barriers/K-tile) -> act -> fp16 gates LDS [gate][h][t-pair]^(h<<2) ->
// pass1: per-thread 32-t (A,B); pass2: in-LDS compose + rescan -> fp32 out direct.
// No pq/carry/final/combine kernels, no 512MB round-trip.
__global__ __launch_bounds__(256, 2)
void qrnn_persist_kernel(const unsigned short* __restrict__ xbf,
                         const unsigned short* __restrict__ wtp,
                         const float* __restrict__ cb,
                         float* __restrict__ out) {
  __shared__ __align__(16) char smem[51712];  // A 16K @0 | B 24K @16384 ; gates 48K overlay; ab @49152

  // XCD swizzle: XCD x gets bid2 in [64x,64x+64) -> 4 consecutive b, all (dir,hb)
  int bid = blockIdx.x;                  // grid = 512
  int bid2 = (bid & 7) * 64 + (bid >> 3);
  int b = bid2 >> 4;
  int v = bid2 & 15;
  int dir = v >> 3, hb = v & 7;
  int nbase = dir * 1536 + hb * 192;     // wt row base
  int obase = dir * 512 + hb * 64;       // out channel base

  int tid = threadIdx.x, lane = tid & 63, wv = tid >> 6;

  // fragment LDS offsets (ks=0; ks=1 addr = offset ^ 64)
  int aoff[2];
#pragma unroll
  for (int mf = 0; mf < 2; ++mf) {
    int row = wv * 32 + mf * 16 + (lane & 15);
    aoff[mf] = row * 128 + (((lane >> 4) * 16) ^ ((row & 7) << 4));
  }
  int boff[12];
#pragma unroll
  for (int j = 0; j < 12; ++j) {
    int row = j * 16 + (lane & 15);
    boff[j] = 16384 + row * 128 + (((lane >> 4) * 16) ^ ((row & 7) << 4));
  }

  // bias (persistent)
  float cbv[12];
#pragma unroll
  for (int j = 0; j < 12; ++j)
    cbv[j] = cb[nbase + j * 16 + (lane & 15)];

  // B staging sources (same panel every chunk -> L2-hot)
  const char* bS[6];
#pragma unroll
  for (int i = 0; i < 6; ++i) {
    int l = tid + 256 * i, row = l >> 3;
    int koff = ((l & 7) * 16) ^ ((row & 7) << 4);
    bS[i] = (const char*)wtp + (size_t)(nbase + row) * 1024 + koff;
  }
  // A staging source row/swizzle (chunk-dependent base added in loop)
  int a_row[4], a_koff[4];
#pragma unroll
  for (int i = 0; i < 4; ++i) {
    int l = tid + 256 * i;
    a_row[i] = l >> 3;
    a_koff[i] = ((l & 7) * 16) ^ ((a_row[i] & 7) << 4);
  }

  int h = tid & 63, sub = tid >> 6;
  const char* zB = smem + h * 256;
  const char* fB = smem + 16384 + h * 256;
  const char* oB = smem + 32768 + h * 256;
  int sx = h << 2;
  float2* abL = (float2*)(smem + 49152);   // [64][5] padded: stride 5

  float c_chunk = 0.f;

  for (int ck = 0; ck < 16; ++ck) {
    size_t m0 = (size_t)b * TT + ck * 128;
    const char* aBase = (const char*)xbf + m0 * 1024;

    f32x4 acc[2][12];
#pragma unroll
    for (int mf = 0; mf < 2; ++mf)
#pragma unroll
      for (int j = 0; j < 12; ++j)
        acc[mf][j] = f32x4{0.f, 0.f, 0.f, 0.f};

    for (int kt = 0; kt < 8; ++kt) {
      __syncthreads();   // kt=0: also protects prev chunk's scan reads (WAR)
      int kb = kt * 128;
#pragma unroll
      for (int i = 0; i < 4; ++i)
        gload16(aBase + (size_t)a_row[i] * 1024 + a_koff[i] + kb, smem + tid * 16 + i * 4096);
#pragma unroll
      for (int i = 0; i < 6; ++i)
        gload16(bS[i] + kb, smem + 16384 + tid * 16 + i * 4096);
      __syncthreads();
#pragma unroll
      for (int ks = 0; ks < 2; ++ks) {
        int kx = ks * 64;
        short8 a0 = *(const short8*)(smem + (aoff[0] ^ kx));
        short8 a1 = *(const short8*)(smem + (aoff[1] ^ kx));
#pragma unroll
        for (int g = 0; g < 3; ++g) {
          short8 b0 = *(const short8*)(smem + (boff[4*g+0] ^ kx));
          short8 b1 = *(const short8*)(smem + (boff[4*g+1] ^ kx));
          short8 b2 = *(const short8*)(smem + (boff[4*g+2] ^ kx));
          short8 b3 = *(const short8*)(smem + (boff[4*g+3] ^ kx));
          acc[0][4*g+0] = __builtin_amdgcn_mfma_f32_16x16x32_bf16(a0, b0, acc[0][4*g+0], 0, 0, 0);
          acc[1][4*g+0] = __builtin_amdgcn_mfma_f32_16x16x32_bf16(a1, b0, acc[1][4*g+0], 0, 0, 0);
          acc[0][4*g+1] = __builtin_amdgcn_mfma_f32_16x16x32_bf16(a0, b1, acc[0][4*g+1], 0, 0, 0);
          acc[1][4*g+1] = __builtin_amdgcn_mfma_f32_16x16x32_bf16(a1, b1, acc[1][4*g+1], 0, 0, 0);
          acc[0][4*g+2] = __builtin_amdgcn_mfma_f32_16x16x32_bf16(a0, b2, acc[0][4*g+2], 0, 0, 0);
          acc[1][4*g+2] = __builtin_amdgcn_mfma_f32_16x16x32_bf16(a1, b2, acc[1][4*g+2], 0, 0, 0);
          acc[0][4*g+3] = __builtin_amdgcn_mfma_f32_16x16x32_bf16(a0, b3, acc[0][4*g+3], 0, 0, 0);
          acc[1][4*g+3] = __builtin_amdgcn_mfma_f32_16x16x32_bf16(a1, b3, acc[1][4*g+3], 0, 0, 0);
        }
      }
    }

    __syncthreads();   // MFMA LDS reads done; overlay gates onto staging LDS

    // gates -> LDS fp16 [gate][h=64 rows of 256B][t-pair u32], byte = (2*t) ^ (h<<2)
#pragma unroll
    for (int mf = 0; mf < 2; ++mf) {
      int base_t = wv * 32 + mf * 16 + (lane >> 4) * 4;
#pragma unroll
      for (int j = 0; j < 12; ++j) {
        int g = j >> 2;
        int hsub = (j & 3) * 16 + (lane & 15);
        float vv[4], a[4];
#pragma unroll
        for (int r = 0; r < 4; ++r) vv[r] = acc[mf][j][r] + cbv[j];
        if (g == 0) {
#pragma unroll
          for (int r = 0; r < 4; ++r) {
            float e = __expf(2.f * vv[r]);
            a[r] = 1.f - 2.f * __builtin_amdgcn_rcpf(e + 1.f);
          }
        } else {
#pragma unroll
          for (int r = 0; r < 4; ++r)
            a[r] = __builtin_amdgcn_rcpf(1.f + __expf(-vv[r]));
        }
        char* gp = smem + g * 16384 + hsub * 256;
        int sw = hsub << 2;
        *(unsigned int*)(gp + ((2 * base_t) ^ sw))     = pkrtz(a[0], a[1]);
        *(unsigned int*)(gp + ((2 * base_t + 4) ^ sw)) = pkrtz(a[2], a[3]);
      }
    }

    __syncthreads();

    // pass 1: thread (h, sub) reduces its 32-t segment to (A,B); caches gate words
    unsigned int zw[16], fw[16];
    float A = 1.f, Bv = 0.f;
#pragma unroll
    for (int i = 0; i < 16; ++i) {
      int byo = (sub * 64 + 4 * i) ^ sx;
      zw[i] = *(const unsigned int*)(zB + byo);
      fw[i] = *(const unsigned int*)(fB + byo);
      float z0 = h2f((unsigned short)zw[i]), z1 = h2f((unsigned short)(zw[i] >> 16));
      float f0 = h2f((unsigned short)fw[i]), f1 = h2f((unsigned short)(fw[i] >> 16));
      Bv = f0 * Bv + (1.f - f0) * z0;
      Bv = f1 * Bv + (1.f - f1) * z1;
      A *= f0 * f1;
    }
    abL[h * 5 + sub] = float2{A, Bv};

    __syncthreads();

    // compose: segment-start c for this sub, and chunk-exit c (identical in all 4 subs)
    float cs = c_chunk, cn = c_chunk;
#pragma unroll
    for (int s = 0; s < 4; ++s) {
      float2 ab = abL[h * 5 + s];
      if (s == sub) cs = cn;
      cn = ab.x * cn + ab.y;
    }
    c_chunk = cn;

    // pass 2: rescan from cs (gate words cached in regs; only o read from LDS), write out
    float c = cs;
    float* op = out + (m0 + sub * 32) * 1024 + obase + h;
#pragma unroll
    for (int i = 0; i < 16; ++i) {
      int byo = (sub * 64 + 4 * i) ^ sx;
      unsigned int oo = *(const unsigned int*)(oB + byo);
      float z0 = h2f((unsigned short)zw[i]), z1 = h2f((unsigned short)(zw[i] >> 16));
      float f0 = h2f((unsigned short)fw[i]), f1 = h2f((unsigned short)(fw[i] >> 16));
      float o0 = h2f((unsigned short)oo), o1 = h2f((unsigned short)(oo >> 16));
      c = f0 * c + (1.f - f0) * z0;
      op[0] = o0 * c;
      c = f1 * c + (1.f - f1) * z1;
      op[1024] = o1 * c;
      op += 2048;
    }
  }
}

// ---------- round-1 fused fallback (tiny-ws path; old W layout) ----------
#define NB 192
#define BT 64
__global__ __launch_bounds__(256, 2)
void qrnn_kernel(const float* __restrict__ x,
                 const float* __restrict__ bf_, const float* __restrict__ bb_,
                 const unsigned short* __restrict__ wt,
                 float* __restrict__ out) {
  __shared__ __align__(16) unsigned short sA[64 * 64];
  __shared__ float sG[64 * 193];
  __shared__ float sBias[NB];
  const int tid  = threadIdx.x;
  const int lane = tid & 63;
  const int wv   = tid >> 6;
  int p = blockIdx.x;
  int xcd = p & 7, slot = p >> 3;
  int b   = xcd * 4 + (slot >> 4);
  int v   = slot & 15;
  int dir = v >> 3, ht = v & 7;
  int h0  = ht * 64;
  if (tid < NB) {
    const float* bsrc = dir ? bb_ : bf_;
    sBias[tid] = bsrc[((tid >> 6) << 9) + h0 + (tid & 63)];
  }
  const float* xb = x + (size_t)b * TT * DD;
  const unsigned short* wtd = wt + (size_t)dir * 1536 * 512;
  size_t brow[3];
#pragma unroll
  for (int j = 0; j < 3; j++) {
    int n = 48 * wv + 16 * j + (lane & 15);
    brow[j] = (size_t)(((n >> 6) << 9) + h0 + (n & 63)) * 512 + 8 * (lane >> 4);
  }
  int a_off[2][4];
#pragma unroll
  for (int kk = 0; kk < 2; kk++)
#pragma unroll
    for (int m = 0; m < 4; m++) {
      int row = 16 * m + (lane & 15);
      a_off[kk][m] = row * 128 + ((64 * kk + 16 * (lane >> 4)) ^ ((row & 7) << 4));
    }
  int s_trow[4], s_kq[4], s_woff[4];
#pragma unroll
  for (int i = 0; i < 4; i++) {
    int q = tid + 256 * i;
    s_trow[i] = q >> 4;
    s_kq[i]   = q & 15;
    s_woff[i] = s_trow[i] * 128 + ((8 * s_kq[i]) ^ ((s_trow[i] & 7) << 4));
  }
  float c = 0.f;
  f32x4 acc[4][3];
  for (int t0 = 0; t0 < TT; t0 += BT) {
#pragma unroll
    for (int m = 0; m < 4; m++)
#pragma unroll
      for (int j = 0; j < 3; j++)
        acc[m][j] = f32x4{0.f, 0.f, 0.f, 0.f};
    float4 vv[4];
#pragma unroll
    for (int i = 0; i < 4; i++)
      vv[i] = *(const float4*)(xb + (size_t)(t0 + s_trow[i]) * DD + 4 * s_kq[i]);
#pragma unroll
    for (int ks = 0; ks < 8; ks++) {
      __syncthreads();
#pragma unroll
      for (int i = 0; i < 4; i++) {
        ushort4 u;
        u.x = f2bf(vv[i].x); u.y = f2bf(vv[i].y);
        u.z = f2bf(vv[i].z); u.w = f2bf(vv[i].w);
        *(ushort4*)((char*)sA + s_woff[i]) = u;
      }
      if (ks < 7) {
        int k0n = (ks + 1) * 64;
#pragma unroll
        for (int i = 0; i < 4; i++)
          vv[i] = *(const float4*)(xb + (size_t)(t0 + s_trow[i]) * DD + k0n + 4 * s_kq[i]);
      }
      __syncthreads();
      const char* sAb = (const char*)sA;
      int k0 = ks * 64;
#pragma unroll
      for (int kk = 0; kk < 2; kk++) {
        short8 bfr[3];
#pragma unroll
        for (int j = 0; j < 3; j++)
          bfr[j] = *(const short8*)(wtd + brow[j] + k0 + 32 * kk);
#pragma unroll
        for (int m = 0; m < 4; m++) {
          short8 afr = *(const short8*)(sAb + a_off[kk][m]);
#pragma unroll
          for (int j = 0; j < 3; j++)
            acc[m][j] = __builtin_amdgcn_mfma_f32_16x16x32_bf16(afr, bfr[j], acc[m][j], 0, 0, 0);
        }
      }
    }
#pragma unroll
    for (int m = 0; m < 4; m++)
#pragma unroll
      for (int j = 0; j < 3; j++) {
        int col   = 48 * wv + 16 * j + (lane & 15);
        int rbase = 16 * m + 4 * (lane >> 4);
#pragma unroll
        for (int r = 0; r < 4; r++)
          sG[(rbase + r) * 193 + col] = acc[m][j][r];
      }
    __syncthreads();
    for (int idx = tid; idx < 64 * NB; idx += 256) {
      int t = idx / NB;
      int n = idx - t * NB;
      float g = sG[t * 193 + n] + sBias[n];
      float res;
      if (n < 64) { float e = __expf(2.f * g); res = 1.f - 2.f / (e + 1.f); }
      else        { res = 1.f / (1.f + __expf(-g)); }
      sG[t * 193 + n] = res;
    }
    __syncthreads();
    if (tid < 64) {
      float* og = out + ((size_t)(b * TT + t0)) * 1024 + (dir << 9) + h0 + tid;
      float cc = c;
#pragma unroll 8
      for (int t = 0; t < BT; t++) {
        float z = sG[t * 193 + tid];
        float f = sG[t * 193 + 64 + tid];
        float o = sG[t * 193 + 128 + tid];
        cc = z + f * (cc - z);
        og[(size_t)t << 10] = o * cc;
      }
      c = cc;
    }
  }
}

extern "C" void kernel_launch(void* const* d_in, const int* in_sizes, int n_in,
                              void* d_out, int out_size, void* d_ws, size_t ws_size,
                              hipStream_t stream) {
  const float* x   = (const float*)d_in[0];
  const float* W_f = (const float*)d_in[1];
  const float* b_f = (const float*)d_in[2];
  const float* W_b = (const float*)d_in[3];
  const float* b_b = (const float*)d_in[4];
  float* out = (float*)d_out;

  char* ws = (char*)d_ws;
  const size_t OFF_WT  = 0;                    // 3 MiB
  const size_t OFF_CB  = 3145728;              // 12 KiB
  const size_t OFF_XBF = 3158016;              // 64 MiB
  const size_t NEED    = OFF_XBF + 67108864ull; // ~70.3 MB

  unsigned short* wt  = (unsigned short*)(ws + OFF_WT);
  float* cbias        = (float*)(ws + OFF_CB);
  unsigned short* xbf = (unsigned short*)(ws + OFF_XBF);

  if (ws_size >= NEED) {
    xconv_kernel<<<16384, 256, 0, stream>>>(x, xbf);
    wtrans_new_kernel<<<1536, 256, 0, stream>>>(W_f, W_b, wt);
    cbias_kernel<<<12, 256, 0, stream>>>(b_f, b_b, cbias);
    qrnn_persist_kernel<<<512, 256, 0, stream>>>(xbf, wt, cbias, out);
  } else {
    wtrans_old_kernel<<<1536, 256, 0, stream>>>(W_f, W_b, wt);
    qrnn_kernel<<<512, 256, 0, stream>>>(x, b_f, b_b, wt, out);
  }
}

// Round 16
// 300.885 us; speedup vs baseline: 2.7017x; 1.0170x over previous
//
#include <hip/hip_runtime.h>
#include <hip/hip_fp16.h>

typedef __attribute__((ext_vector_type(8))) short short8;
typedef __attribute__((ext_vector_type(4))) float f32x4;

#define TT 2048
#define DD 512

__device__ __forceinline__ unsigned short f2bf(float f) {
  unsigned int u = __float_as_uint(f);
  u += 0x7FFFu + ((u >> 16) & 1u);
  return (unsigned short)(u >> 16);
}
__device__ __forceinline__ float h2f(unsigned short u) {
  return __half2float(__ushort_as_half(u));
}
__device__ __forceinline__ unsigned int pkrtz(float a, float b) {
  auto r = __builtin_amdgcn_cvt_pkrtz(a, b);   // __fp16 ext_vector_type(2)
  return __builtin_bit_cast(unsigned int, r);
}
__device__ __forceinline__ void gload16(const void* g, void* l) {
  __builtin_amdgcn_global_load_lds((const __attribute__((address_space(1))) void*)g,
                                   (__attribute__((address_space(3))) void*)l, 16, 0, 0);
}

// ---------- prep kernels ----------

__global__ void xconv_kernel(const float* __restrict__ x, unsigned short* __restrict__ xbf) {
  int i = blockIdx.x * 256 + threadIdx.x;
  const float4* p = (const float4*)x + (size_t)i * 2;
  float4 a = p[0], b = p[1];
  short8 o;
  o[0] = f2bf(a.x); o[1] = f2bf(a.y); o[2] = f2bf(a.z); o[3] = f2bf(a.w);
  o[4] = f2bf(b.x); o[5] = f2bf(b.y); o[6] = f2bf(b.z); o[7] = f2bf(b.w);
  *((short8*)xbf + i) = o;
}

// W[512][1536] fp32 -> Wt[dir][n'][512 k] bf16, n' = (h>>6)*192 + gate*64 + (h&63)
__global__ void wtrans_new_kernel(const float* __restrict__ Wf,
                                  const float* __restrict__ Wb,
                                  unsigned short* __restrict__ wt) {
  __shared__ float tile[32][33];
  int bid = blockIdx.x;            // 2 * 16 * 48
  int d   = bid / 768;
  int rem = bid - d * 768;
  int kt = rem & 15;
  int ct = rem >> 4;
  const float* W = d ? Wb : Wf;
  int k0 = kt * 32, c0 = ct * 32;
  int r = threadIdx.x >> 5, c = threadIdx.x & 31;
#pragma unroll
  for (int i = 0; i < 4; i++)
    tile[r + 8*i][c] = W[(size_t)(k0 + r + 8*i) * 1536 + c0 + c];
  __syncthreads();
#pragma unroll
  for (int i = 0; i < 4; i++) {
    int col = c0 + r + 8*i;
    int gate = col >> 9, hh = col & 511;
    int nn = (hh >> 6) * 192 + gate * 64 + (hh & 63);
    wt[((size_t)d * 1536 + nn) * 512 + k0 + c] = f2bf(tile[c][r + 8*i]);
  }
}

// old layout for fallback kernel
__global__ void wtrans_old_kernel(const float* __restrict__ Wf,
                                  const float* __restrict__ Wb,
                                  unsigned short* __restrict__ wt) {
  __shared__ float tile[32][33];
  int bid = blockIdx.x;
  int d   = bid / 768;
  int rem = bid - d * 768;
  int kt = rem & 15;
  int ct = rem >> 4;
  const float* W = d ? Wb : Wf;
  int k0 = kt * 32, c0 = ct * 32;
  int r = threadIdx.x >> 5, c = threadIdx.x & 31;
#pragma unroll
  for (int i = 0; i < 4; i++)
    tile[r + 8*i][c] = W[(size_t)(k0 + r + 8*i) * 1536 + c0 + c];
  __syncthreads();
  unsigned short* outp = wt + ((size_t)d * 1536 + c0) * 512 + k0;
#pragma unroll
  for (int i = 0; i < 4; i++)
    outp[(size_t)(r + 8*i) * 512 + c] = f2bf(tile[c][r + 8*i]);
}

__global__ void cbias_kernel(const float* __restrict__ bf_, const float* __restrict__ bb_,
                             float* __restrict__ cb) {
  int t = blockIdx.x * 256 + threadIdx.x;   // 3072
  int d = t / 1536, cc = t - d * 1536;
  int gate = cc >> 9, hh = cc & 511;
  int nn = (hh >> 6) * 192 + gate * 64 + (hh & 63);
  cb[d * 1536 + nn] = (d ? bb_ : bf_)[cc];
}

// ---------- persistent fused GEMM + activation + full fo-pool scan + direct out ----------
// Round-15 structure with ONE change: BK=128 (4 K-tiles/chunk instead of 8).
// Occupancy is grid-capped at 2 blocks/CU (512 blocks), so the 80KB LDS costs nothing;
// barrier+vmcnt-drain count per chunk halves (16 -> 8). Same schedule otherwise.
// LDS: A [128][256B] @0 (32K) | B [192][256B] @32768 (48K) = 81920 B.
// Gates overlay z@0 f@16384 o@32768 ; abL @49152 (all < 81920, round-15-identical).
__global__ __launch_bounds__(256, 2)
void qrnn_persist_kernel(const unsigned short* __restrict__ xbf,
                         const unsigned short* __restrict__ wtp,
                         const float* __restrict__ cb,
                         float* __restrict__ out) {
  __shared__ __align__(16) char smem[81920];

  // XCD swizzle: XCD x gets bid2 in [64x,64x+64) -> 4 consecutive b, all (dir,hb)
  int bid = blockIdx.x;                  // grid = 512
  int bid2 = (bid & 7) * 64 + (bid >> 3);
  int b = bid2 >> 4;
  int v = bid2 & 15;
  int dir = v >> 3, hb = v & 7;
  int nbase = dir * 1536 + hb * 192;     // wt row base
  int obase = dir * 512 + hb * 64;       // out channel base

  int tid = threadIdx.x, lane = tid & 63, wv = tid >> 6;
  int l15 = lane & 15, q16 = (lane >> 4) * 16;

  // fragment bases (rows of 256B); read addr = base + ((ks*64 + q16) ^ sw)
  int baseA[2], swA[2];
#pragma unroll
  for (int mf = 0; mf < 2; ++mf) {
    int row = wv * 32 + mf * 16 + l15;
    baseA[mf] = row * 256;
    swA[mf] = (row & 7) << 4;
  }
  int baseB[12], swB[12];
#pragma unroll
  for (int j = 0; j < 12; ++j) {
    int row = j * 16 + l15;
    baseB[j] = 32768 + row * 256;
    swB[j] = (row & 7) << 4;
  }

  // bias (persistent)
  float cbv[12];
#pragma unroll
  for (int j = 0; j < 12; ++j)
    cbv[j] = cb[nbase + j * 16 + l15];

  // staging offsets (linear LDS dest, inverse-swizzled source; rows are 1024B in global)
  int a_off[8];
#pragma unroll
  for (int i = 0; i < 8; ++i) {
    int p = tid * 16 + i * 4096;
    int row = p >> 8;
    a_off[i] = row * 1024 + ((p & 255) ^ ((row & 7) << 4));
  }
  int b_off[12];
#pragma unroll
  for (int i = 0; i < 12; ++i) {
    int p = tid * 16 + i * 4096;
    int row = p >> 8;
    b_off[i] = (nbase + row) * 1024 + ((p & 255) ^ ((row & 7) << 4));
  }
  const char* wbytes = (const char*)wtp;

  int h = tid & 63, sub = tid >> 6;
  const char* zB = smem + h * 256;
  const char* fB = smem + 16384 + h * 256;
  const char* oB = smem + 32768 + h * 256;
  int sx = h << 2;
  float2* abL = (float2*)(smem + 49152);   // [64][5] padded: stride 5

  float c_chunk = 0.f;

  for (int ck = 0; ck < 16; ++ck) {
    size_t m0 = (size_t)b * TT + ck * 128;
    const char* aBase = (const char*)xbf + m0 * 1024;

    f32x4 acc[2][12];
#pragma unroll
    for (int mf = 0; mf < 2; ++mf)
#pragma unroll
      for (int j = 0; j < 12; ++j)
        acc[mf][j] = f32x4{0.f, 0.f, 0.f, 0.f};

    for (int kt = 0; kt < 4; ++kt) {
      __syncthreads();   // kt=0: also protects prev chunk's scan reads (WAR)
      int kb = kt * 256;
#pragma unroll
      for (int i = 0; i < 8; ++i)
        gload16(aBase + a_off[i] + kb, smem + tid * 16 + i * 4096);
#pragma unroll
      for (int i = 0; i < 12; ++i)
        gload16(wbytes + b_off[i] + kb, smem + 32768 + tid * 16 + i * 4096);
      __syncthreads();   // gload_lds data landed for all waves (one drain per 96 MFMA)
#pragma unroll
      for (int ks = 0; ks < 4; ++ks) {
        int kx = ks * 64;
        short8 a0 = *(const short8*)(smem + baseA[0] + ((kx + q16) ^ swA[0]));
        short8 a1 = *(const short8*)(smem + baseA[1] + ((kx + q16) ^ swA[1]));
#pragma unroll
        for (int g = 0; g < 3; ++g) {
          short8 b0 = *(const short8*)(smem + baseB[4*g+0] + ((kx + q16) ^ swB[4*g+0]));
          short8 b1 = *(const short8*)(smem + baseB[4*g+1] + ((kx + q16) ^ swB[4*g+1]));
          short8 b2 = *(const short8*)(smem + baseB[4*g+2] + ((kx + q16) ^ swB[4*g+2]));
          short8 b3 = *(const short8*)(smem + baseB[4*g+3] + ((kx + q16) ^ swB[4*g+3]));
          acc[0][4*g+0] = __builtin_amdgcn_mfma_f32_16x16x32_bf16(a0, b0, acc[0][4*g+0], 0, 0, 0);
          acc[1][4*g+0] = __builtin_amdgcn_mfma_f32_16x16x32_bf16(a1, b0, acc[1][4*g+0], 0, 0, 0);
          acc[0][4*g+1] = __builtin_amdgcn_mfma_f32_16x16x32_bf16(a0, b1, acc[0][4*g+1], 0, 0, 0);
          acc[1][4*g+1] = __builtin_amdgcn_mfma_f32_16x16x32_bf16(a1, b1, acc[1][4*g+1], 0, 0, 0);
          acc[0][4*g+2] = __builtin_amdgcn_mfma_f32_16x16x32_bf16(a0, b2, acc[0][4*g+2], 0, 0, 0);
          acc[1][4*g+2] = __builtin_amdgcn_mfma_f32_16x16x32_bf16(a1, b2, acc[1][4*g+2], 0, 0, 0);
          acc[0][4*g+3] = __builtin_amdgcn_mfma_f32_16x16x32_bf16(a0, b3, acc[0][4*g+3], 0, 0, 0);
          acc[1][4*g+3] = __builtin_amdgcn_mfma_f32_16x16x32_bf16(a1, b3, acc[1][4*g+3], 0, 0, 0);
        }
      }
    }

    __syncthreads();   // MFMA LDS reads done; overlay gates onto staging LDS

    // gates -> LDS fp16 [gate][h=64 rows of 256B][t-pair u32], byte = (2*t) ^ (h<<2)
#pragma unroll
    for (int mf = 0; mf < 2; ++mf) {
      int base_t = wv * 32 + mf * 16 + (lane >> 4) * 4;
#pragma unroll
      for (int j = 0; j < 12; ++j) {
        int g = j >> 2;
        int hsub = (j & 3) * 16 + l15;
        float vv[4], a[4];
#pragma unroll
        for (int r = 0; r < 4; ++r) vv[r] = acc[mf][j][r] + cbv[j];
        if (g == 0) {
#pragma unroll
          for (int r = 0; r < 4; ++r) {
            float e = __expf(2.f * vv[r]);
            a[r] = 1.f - 2.f * __builtin_amdgcn_rcpf(e + 1.f);
          }
        } else {
#pragma unroll
          for (int r = 0; r < 4; ++r)
            a[r] = __builtin_amdgcn_rcpf(1.f + __expf(-vv[r]));
        }
        char* gp = smem + g * 16384 + hsub * 256;
        int sw = hsub << 2;
        *(unsigned int*)(gp + ((2 * base_t) ^ sw))     = pkrtz(a[0], a[1]);
        *(unsigned int*)(gp + ((2 * base_t + 4) ^ sw)) = pkrtz(a[2], a[3]);
      }
    }

    __syncthreads();

    // pass 1: thread (h, sub) reduces its 32-t segment to (A,B); caches gate words
    unsigned int zw[16], fw[16];
    float A = 1.f, Bv = 0.f;
#pragma unroll
    for (int i = 0; i < 16; ++i) {
      int byo = (sub * 64 + 4 * i) ^ sx;
      zw[i] = *(const unsigned int*)(zB + byo);
      fw[i] = *(const unsigned int*)(fB + byo);
      float z0 = h2f((unsigned short)zw[i]), z1 = h2f((unsigned short)(zw[i] >> 16));
      float f0 = h2f((unsigned short)fw[i]), f1 = h2f((unsigned short)(fw[i] >> 16));
      Bv = f0 * Bv + (1.f - f0) * z0;
      Bv = f1 * Bv + (1.f - f1) * z1;
      A *= f0 * f1;
    }
    abL[h * 5 + sub] = float2{A, Bv};

    __syncthreads();

    // compose: segment-start c for this sub, and chunk-exit c (identical in all 4 subs)
    float cs = c_chunk, cn = c_chunk;
#pragma unroll
    for (int s = 0; s < 4; ++s) {
      float2 ab = abL[h * 5 + s];
      if (s == sub) cs = cn;
      cn = ab.x * cn + ab.y;
    }
    c_chunk = cn;

    // pass 2: rescan from cs (gate words cached in regs; only o read from LDS), write out
    float c = cs;
    float* op = out + (m0 + sub * 32) * 1024 + obase + h;
#pragma unroll
    for (int i = 0; i < 16; ++i) {
      int byo = (sub * 64 + 4 * i) ^ sx;
      unsigned int oo = *(const unsigned int*)(oB + byo);
      float z0 = h2f((unsigned short)zw[i]), z1 = h2f((unsigned short)(zw[i] >> 16));
      float f0 = h2f((unsigned short)fw[i]), f1 = h2f((unsigned short)(fw[i] >> 16));
      float o0 = h2f((unsigned short)oo), o1 = h2f((unsigned short)(oo >> 16));
      c = f0 * c + (1.f - f0) * z0;
      op[0] = o0 * c;
      c = f1 * c + (1.f - f1) * z1;
      op[1024] = o1 * c;
      op += 2048;
    }
  }
}

// ---------- round-1 fused fallback (tiny-ws path; old W layout) ----------
#define NB 192
#define BT 64
__global__ __launch_bounds__(256, 2)
void qrnn_kernel(const float* __restrict__ x,
                 const float* __restrict__ bf_, const float* __restrict__ bb_,
                 const unsigned short* __restrict__ wt,
                 float* __restrict__ out) {
  __shared__ __align__(16) unsigned short sA[64 * 64];
  __shared__ float sG[64 * 193];
  __shared__ float sBias[NB];
  const int tid  = threadIdx.x;
  const int lane = tid & 63;
  const int wv   = tid >> 6;
  int p = blockIdx.x;
  int xcd = p & 7, slot = p >> 3;
  int b   = xcd * 4 + (slot >> 4);
  int v   = slot & 15;
  int dir = v >> 3, ht = v & 7;
  int h0  = ht * 64;
  if (tid < NB) {
    const float* bsrc = dir ? bb_ : bf_;
    sBias[tid] = bsrc[((tid >> 6) << 9) + h0 + (tid & 63)];
  }
  const float* xb = x + (size_t)b * TT * DD;
  const unsigned short* wtd = wt + (size_t)dir * 1536 * 512;
  size_t brow[3];
#pragma unroll
  for (int j = 0; j < 3; j++) {
    int n = 48 * wv + 16 * j + (lane & 15);
    brow[j] = (size_t)(((n >> 6) << 9) + h0 + (n & 63)) * 512 + 8 * (lane >> 4);
  }
  int a_off[2][4];
#pragma unroll
  for (int kk = 0; kk < 2; kk++)
#pragma unroll
    for (int m = 0; m < 4; m++) {
      int row = 16 * m + (lane & 15);
      a_off[kk][m] = row * 128 + ((64 * kk + 16 * (lane >> 4)) ^ ((row & 7) << 4));
    }
  int s_trow[4], s_kq[4], s_woff[4];
#pragma unroll
  for (int i = 0; i < 4; i++) {
    int q = tid + 256 * i;
    s_trow[i] = q >> 4;
    s_kq[i]   = q & 15;
    s_woff[i] = s_trow[i] * 128 + ((8 * s_kq[i]) ^ ((s_trow[i] & 7) << 4));
  }
  float c = 0.f;
  f32x4 acc[4][3];
  for (int t0 = 0; t0 < TT; t0 += BT) {
#pragma unroll
    for (int m = 0; m < 4; m++)
#pragma unroll
      for (int j = 0; j < 3; j++)
        acc[m][j] = f32x4{0.f, 0.f, 0.f, 0.f};
    float4 vv[4];
#pragma unroll
    for (int i = 0; i < 4; i++)
      vv[i] = *(const float4*)(xb + (size_t)(t0 + s_trow[i]) * DD + 4 * s_kq[i]);
#pragma unroll
    for (int ks = 0; ks < 8; ks++) {
      __syncthreads();
#pragma unroll
      for (int i = 0; i < 4; i++) {
        ushort4 u;
        u.x = f2bf(vv[i].x); u.y = f2bf(vv[i].y);
        u.z = f2bf(vv[i].z); u.w = f2bf(vv[i].w);
        *(ushort4*)((char*)sA + s_woff[i]) = u;
      }
      if (ks < 7) {
        int k0n = (ks + 1) * 64;
#pragma unroll
        for (int i = 0; i < 4; i++)
          vv[i] = *(const float4*)(xb + (size_t)(t0 + s_trow[i]) * DD + k0n + 4 * s_kq[i]);
      }
      __syncthreads();
      const char* sAb = (const char*)sA;
      int k0 = ks * 64;
#pragma unroll
      for (int kk = 0; kk < 2; kk++) {
        short8 bfr[3];
#pragma unroll
        for (int j = 0; j < 3; j++)
          bfr[j] = *(const short8*)(wtd + brow[j] + k0 + 32 * kk);
#pragma unroll
        for (int m = 0; m < 4; m++) {
          short8 afr = *(const short8*)(sAb + a_off[kk][m]);
#pragma unroll
          for (int j = 0; j < 3; j++)
            acc[m][j] = __builtin_amdgcn_mfma_f32_16x16x32_bf16(afr, bfr[j], acc[m][j], 0, 0, 0);
        }
      }
    }
#pragma unroll
    for (int m = 0; m < 4; m++)
#pragma unroll
      for (int j = 0; j < 3; j++) {
        int col   = 48 * wv + 16 * j + (lane & 15);
        int rbase = 16 * m + 4 * (lane >> 4);
#pragma unroll
        for (int r = 0; r < 4; r++)
          sG[(rbase + r) * 193 + col] = acc[m][j][r];
      }
    __syncthreads();
    for (int idx = tid; idx < 64 * NB; idx += 256) {
      int t = idx / NB;
      int n = idx - t * NB;
      float g = sG[t * 193 + n] + sBias[n];
      float res;
      if (n < 64) { float e = __expf(2.f * g); res = 1.f - 2.f / (e + 1.f); }
      else        { res = 1.f / (1.f + __expf(-g)); }
      sG[t * 193 + n] = res;
    }
    __syncthreads();
    if (tid < 64) {
      float* og = out + ((size_t)(b * TT + t0)) * 1024 + (dir << 9) + h0 + tid;
      float cc = c;
#pragma unroll 8
      for (int t = 0; t < BT; t++) {
        float z = sG[t * 193 + tid];
        float f = sG[t * 193 + 64 + tid];
        float o = sG[t * 193 + 128 + tid];
        cc = z + f * (cc - z);
        og[(size_t)t << 10] = o * cc;
      }
      c = cc;
    }
  }
}

extern "C" void kernel_launch(void* const* d_in, const int* in_sizes, int n_in,
                              void* d_out, int out_size, void* d_ws, size_t ws_size,
                              hipStream_t stream) {
  const float* x   = (const float*)d_in[0];
  const float* W_f = (const float*)d_in[1];
  const float* b_f = (const float*)d_in[2];
  const float* W_b = (const float*)d_in[3];
  const float* b_b = (const float*)d_in[4];
  float* out = (float*)d_out;

  char* ws = (char*)d_ws;
  const size_t OFF_WT  = 0;                    // 3 MiB
  const size_t OFF_CB  = 3145728;              // 12 KiB
  const size_t OFF_XBF = 3158016;              // 64 MiB
  const size_t NEED    = OFF_XBF + 67108864ull; // ~70.3 MB

  unsigned short* wt  = (unsigned short*)(ws + OFF_WT);
  float* cbias        = (float*)(ws + OFF_CB);
  unsigned short* xbf = (unsigned short*)(ws + OFF_XBF);

  if (ws_size >= NEED) {
    xconv_kernel<<<16384, 256, 0, stream>>>(x, xbf);
    wtrans_new_kernel<<<1536, 256, 0, stream>>>(W_f, W_b, wt);
    cbias_kernel<<<12, 256, 0, stream>>>(b_f, b_b, cbias);
    qrnn_persist_kernel<<<512, 256, 0, stream>>>(xbf, wt, cbias, out);
  } else {
    wtrans_old_kernel<<<1536, 256, 0, stream>>>(W_f, W_b, wt);
    qrnn_kernel<<<512, 256, 0, stream>>>(x, b_f, b_b, wt, out);
  }
}